// Round 4
// baseline (1233.265 us; speedup 1.0000x reference)
//
#include <hip/hip_runtime.h>
#include <hip/hip_bf16.h>

#define NNUE_INPUTS 41024
#define L1N 128
#define L2N 32
#define L3N 32
#define MAX_ACT 512     // per-perspective capacity; mean ~30 actives
#define NV8 (NNUE_INPUTS / 8)      // 5128 chunks of 8 floats (32B)
#define BULK 20                    // 20*256 = 5120 uniform chunks; tail = 8

__device__ __forceinline__ float clip01(float x) {
    return fminf(fmaxf(x, 0.0f), 1.0f);
}

__global__ __launch_bounds__(256, 4) void nnue_fused_kernel(
    const float* __restrict__ us, const float* __restrict__ them,
    const float* __restrict__ w_in, const float* __restrict__ b_in,
    const float* __restrict__ W_ft, const float* __restrict__ b_ft,
    const float* __restrict__ W1, const float* __restrict__ b1,
    const float* __restrict__ W2, const float* __restrict__ b2,
    const float* __restrict__ Wo, const float* __restrict__ bo,
    float* __restrict__ out)
{
    __shared__ int   s_idx_w[MAX_ACT];
    __shared__ int   s_idx_b[MAX_ACT];
    __shared__ int   s_cnt[2];
    __shared__ float s_w[L1N];
    __shared__ float s_b[L1N];
    __shared__ float s_l0[2 * L1N];
    __shared__ float s_part[8][L2N];
    __shared__ float s_l1[L2N];
    __shared__ float s_l2[L3N];

    const int row = blockIdx.x;
    const int tid = threadIdx.x;

    if (tid < 2) s_cnt[tid] = 0;
    const float u = us[row];
    const float t = them[row];
    __syncthreads();

    const float4* wr = (const float4*)(w_in + (size_t)row * NNUE_INPUTS);
    const float4* br = (const float4*)(b_in + (size_t)row * NNUE_INPUTS);

    auto process = [&](int v, const float4& a0, const float4& a1,
                              const float4& c0, const float4& c1) {
        const float sw = ((a0.x + a0.y) + (a0.z + a0.w)) + ((a1.x + a1.y) + (a1.z + a1.w));
        const float sb = ((c0.x + c0.y) + (c0.z + c0.w)) + ((c1.x + c1.y) + (c1.z + c1.w));
        if (__any((sw != 0.0f) || (sb != 0.0f))) {
            const int base = v * 8;
            if (sw != 0.0f) {
                unsigned m = (a0.x != 0.0f ?   1u : 0u) | (a0.y != 0.0f ?   2u : 0u)
                           | (a0.z != 0.0f ?   4u : 0u) | (a0.w != 0.0f ?   8u : 0u)
                           | (a1.x != 0.0f ?  16u : 0u) | (a1.y != 0.0f ?  32u : 0u)
                           | (a1.z != 0.0f ?  64u : 0u) | (a1.w != 0.0f ? 128u : 0u);
                while (m) {
                    const int b = __ffs(m) - 1; m &= m - 1;
                    const int p = atomicAdd(&s_cnt[0], 1);
                    s_idx_w[p & (MAX_ACT - 1)] = base + b;
                }
            }
            if (sb != 0.0f) {
                unsigned m = (c0.x != 0.0f ?   1u : 0u) | (c0.y != 0.0f ?   2u : 0u)
                           | (c0.z != 0.0f ?   4u : 0u) | (c0.w != 0.0f ?   8u : 0u)
                           | (c1.x != 0.0f ?  16u : 0u) | (c1.y != 0.0f ?  32u : 0u)
                           | (c1.z != 0.0f ?  64u : 0u) | (c1.w != 0.0f ? 128u : 0u);
                while (m) {
                    const int b = __ffs(m) - 1; m &= m - 1;
                    const int p = atomicAdd(&s_cnt[1], 1);
                    s_idx_b[p & (MAX_ACT - 1)] = base + b;
                }
            }
        }
    };

    // ---- Phase 1: distance-2 software-pipelined scan.
    // 3-slot rotating buffer; at each wait point, 8 loads (2 iterations ahead)
    // remain in flight -> 8 KB/wave steady-state outstanding.
    {
        float4 sa0[3], sa1[3], sc0[3], sc1[3];
        {
            const int v0 = tid, v1 = tid + 256;
            sa0[0] = wr[2 * v0]; sa1[0] = wr[2 * v0 + 1];
            sc0[0] = br[2 * v0]; sc1[0] = br[2 * v0 + 1];
            sa0[1] = wr[2 * v1]; sa1[1] = wr[2 * v1 + 1];
            sc0[1] = br[2 * v1]; sc1[1] = br[2 * v1 + 1];
        }
        #pragma unroll 3
        for (int i = 0; i < BULK - 2; ++i) {
            const int vp = tid + (i + 2) * 256;       // prefetch 2 ahead
            const int lp = (i + 2) % 3;
            sa0[lp] = wr[2 * vp]; sa1[lp] = wr[2 * vp + 1];
            sc0[lp] = br[2 * vp]; sc1[lp] = br[2 * vp + 1];
            const int lc = i % 3;
            process(tid + i * 256, sa0[lc], sa1[lc], sc0[lc], sc1[lc]);
        }
        {
            const int i = BULK - 2, lc = i % 3;
            process(tid + i * 256, sa0[lc], sa1[lc], sc0[lc], sc1[lc]);
        }
        {
            const int i = BULK - 1, lc = i % 3;
            process(tid + i * 256, sa0[lc], sa1[lc], sc0[lc], sc1[lc]);
        }
        // tail: chunks [5120, 5128) on threads 0..7
        const int vt = BULK * 256 + tid;
        if (vt < NV8) {
            process(vt, wr[2 * vt], wr[2 * vt + 1], br[2 * vt], br[2 * vt + 1]);
        }
    }
    __syncthreads();

    const int kw = min(s_cnt[0], MAX_ACT);
    const int kb = min(s_cnt[1], MAX_ACT);

    // ---- Phase 2: gather W_ft rows; unroll-4 independent loads ----
    {
        const int  c    = tid & (L1N - 1);
        const bool is_b = tid >= L1N;
        const int* lst  = is_b ? s_idx_b : s_idx_w;
        const int  K    = is_b ? kb : kw;
        const float* Wc = W_ft + c;
        float acc = b_ft[c];
        int k = 0;
        for (; k + 4 <= K; k += 4) {
            const int i0 = lst[k], i1 = lst[k + 1], i2 = lst[k + 2], i3 = lst[k + 3];
            const float f0 = Wc[(size_t)i0 * L1N];
            const float f1 = Wc[(size_t)i1 * L1N];
            const float f2 = Wc[(size_t)i2 * L1N];
            const float f3 = Wc[(size_t)i3 * L1N];
            acc += f0; acc += f1; acc += f2; acc += f3;
        }
        for (; k < K; ++k) acc += Wc[(size_t)lst[k] * L1N];
        if (is_b) s_b[c] = acc; else s_w[c] = acc;
    }
    __syncthreads();

    // ---- Phase 3: perspective mix + clip -> l0 [256] ----
    if (tid < L1N) {
        const float wv = s_w[tid], bv = s_b[tid];
        s_l0[tid]       = clip01(u * wv + t * bv);
        s_l0[L1N + tid] = clip01(u * bv + t * wv);
    }
    __syncthreads();

    // ---- l1 = clip(l0 @ W1 + b1): 256 threads = 8 chunks x 32 outputs ----
    {
        const int o  = tid & 31;
        const int ch = tid >> 5;
        float a = 0.0f;
        const int k0 = ch * 32;
        #pragma unroll
        for (int k = 0; k < 32; ++k) {
            a += s_l0[k0 + k] * W1[(k0 + k) * L2N + o];
        }
        s_part[ch][o] = a;
    }
    __syncthreads();
    if (tid < L2N) {
        float a = b1[tid];
        #pragma unroll
        for (int j = 0; j < 8; ++j) a += s_part[j][tid];
        s_l1[tid] = clip01(a);
    }
    __syncthreads();

    // ---- l2 = clip(l1 @ W2 + b2) ----
    if (tid < L3N) {
        float a = b2[tid];
        #pragma unroll
        for (int k = 0; k < L2N; ++k) a += s_l1[k] * W2[k * L3N + tid];
        s_l2[tid] = clip01(a);
    }
    __syncthreads();

    // ---- out = l2 @ Wo + bo ----
    if (tid == 0) {
        float a = bo[0];
        #pragma unroll
        for (int k = 0; k < L3N; ++k) a += s_l2[k] * Wo[k];
        out[row] = a;
    }
}

extern "C" void kernel_launch(void* const* d_in, const int* in_sizes, int n_in,
                              void* d_out, int out_size, void* d_ws, size_t ws_size,
                              hipStream_t stream) {
    const float* us   = (const float*)d_in[0];
    const float* them = (const float*)d_in[1];
    const float* w_in = (const float*)d_in[2];
    const float* b_in = (const float*)d_in[3];
    const float* W_ft = (const float*)d_in[4];
    const float* b_ft = (const float*)d_in[5];
    const float* W1   = (const float*)d_in[6];
    const float* b1   = (const float*)d_in[7];
    const float* W2   = (const float*)d_in[8];
    const float* b2   = (const float*)d_in[9];
    const float* Wo   = (const float*)d_in[10];
    const float* bo   = (const float*)d_in[11];
    float* out = (float*)d_out;

    const int B = in_sizes[0];  // 4096
    nnue_fused_kernel<<<dim3(B), dim3(256), 0, stream>>>(
        us, them, w_in, b_in, W_ft, b_ft, W1, b1, W2, b2, Wo, bo, out);
}